// Round 6
// baseline (251.021 us; speedup 1.0000x reference)
//
#include <hip/hip_runtime.h>
#include <hip/hip_bf16.h>

// Problem constants
#define BB 2
#define SS 2048
#define HH 1024
#define NHH 16
#define HDD 64
#define MM (BB*SS)        // 4096
#define QKV_N (3*HH)      // 3072

typedef _Float16 f16x8 __attribute__((ext_vector_type(8)));
typedef _Float16 f16x4 __attribute__((ext_vector_type(4)));
typedef float f32x4 __attribute__((ext_vector_type(4)));

#define MFMA16(a,b,c)  __builtin_amdgcn_mfma_f32_16x16x32_f16((a),(b),(c),0,0,0)
#define MFMA16K16(a,b,c) __builtin_amdgcn_mfma_f32_16x16x16f16((a),(b),(c),0,0,0)

// async global->LDS 16B per lane; LDS dest = wave-uniform base + lane*16
__device__ __forceinline__ void gl2lds16(const _Float16* g, _Float16* l) {
    __builtin_amdgcn_global_load_lds(
        (const __attribute__((address_space(1))) void*)g,
        (__attribute__((address_space(3))) void*)l, 16, 0, 0);
}

// single-instruction exp2 WITH compiler hazard handling (raw asm broke TRANS-op waits)
__device__ __forceinline__ float fexp2(float x) { return __builtin_amdgcn_exp2f(x); }

// ---------------- prep: z<4 transpose-cast W; z==4 cast X; z==5 zero Out ---------------
// grid (16,16,6), block 256. z==5 zeroes the fp32 output for the split-K atomic GEMM.
__global__ __launch_bounds__(256) void prep_kernel(
    const float* __restrict__ X,
    const float* __restrict__ W0, const float* __restrict__ W1,
    const float* __restrict__ W2, const float* __restrict__ W3,
    _Float16* __restrict__ Xh,
    _Float16* __restrict__ WqkvT, _Float16* __restrict__ WoT,
    float* __restrict__ OutZ)
{
    __shared__ float t[64][65];
    int z = blockIdx.z;
    int tid = threadIdx.x;
    if (z == 4) {
        int base = (blockIdx.y * 16 + blockIdx.x) * 256 + tid;
        const float4* xin = (const float4*)X;
        f16x4* xout = (f16x4*)Xh;
#pragma unroll
        for (int i = 0; i < 16; ++i) {
            float4 v = xin[base + i * 65536];
            f16x4 hh = {(_Float16)v.x, (_Float16)v.y, (_Float16)v.z, (_Float16)v.w};
            xout[base + i * 65536] = hh;
        }
        return;
    }
    if (z == 5) {                        // zero 4096x1024 fp32 output (16 MB)
        int base = (blockIdx.y * 16 + blockIdx.x) * 256 + tid;
        float4* o4 = (float4*)OutZ;
        float4 zv = {0.f, 0.f, 0.f, 0.f};
#pragma unroll
        for (int i = 0; i < 16; ++i) o4[base + i * 65536] = zv;
        return;
    }
    const float* src = (z == 0) ? W0 : (z == 1) ? W1 : (z == 2) ? W2 : W3;
    _Float16* dst = (z < 3) ? (WqkvT + (size_t)z * HH * HH) : WoT;
    int k0 = blockIdx.y * 64, n0 = blockIdx.x * 64;
#pragma unroll
    for (int p = 0; p < 4; ++p) {
        int row = p * 16 + (tid >> 4);
        int col4 = (tid & 15) * 4;
        float4 v = *(const float4*)&src[(size_t)(k0 + row) * HH + n0 + col4];
        t[row][col4 + 0] = v.x; t[row][col4 + 1] = v.y;
        t[row][col4 + 2] = v.z; t[row][col4 + 3] = v.w;
    }
    __syncthreads();
#pragma unroll
    for (int p = 0; p < 2; ++p) {
        int nc = p * 32 + (tid >> 3);
        int ch = tid & 7;
        f16x8 o;
#pragma unroll
        for (int j = 0; j < 8; ++j) o[j] = (_Float16)t[ch * 8 + j][nc];
        *(f16x8*)&dst[(size_t)(n0 + nc) * HH + k0 + ch * 8] = o;
    }
}

// ---------------- QKV GEMM: 128x128 tile, 3-stage pipeline (proven 43.5us) -------------
// (2-stage experiment reverted: grid 768 = exactly 3 blocks/CU, so the 32KB-LDS
//  occupancy theory was void — it only cut pipeline depth, 43.5 -> 44.8 us.)
__global__ __launch_bounds__(256) void gemm_qkv_kernel(
    const _Float16* __restrict__ A, const _Float16* __restrict__ Bt,
    const float* __restrict__ bias0, const float* __restrict__ bias1, const float* __restrict__ bias2,
    _Float16* __restrict__ Qh, _Float16* __restrict__ Kh, _Float16* __restrict__ Vt)
{
    const int K = HH;
    const int NT = K / 32;
    __shared__ _Float16 smem[24576];          // 49152 B: 3-stage bufs U epilogue tile 128x132

    int row0 = blockIdx.y * 128, n0 = blockIdx.x * 128;
    int tid = threadIdx.x;
    int w = tid >> 6, l = tid & 63, m16 = l & 15, quad = l >> 4;
    int wm = w >> 1, wn = w & 1;

    int srow = w * 32 + (l >> 2);
    int sch = (l & 3) ^ ((l >> 2) & 3) ^ ((l >> 4) & 3);
    const _Float16* aptr = A + (size_t)(row0 + srow) * K + sch * 8;
    const _Float16* bptr = Bt + (size_t)(n0 + srow) * K + sch * 8;

    int gsw = (m16 & 3) ^ ((m16 >> 2) & 3);
    int acol = (quad ^ gsw) * 8;

    f32x4 zero4 = {0.f, 0.f, 0.f, 0.f};
    f32x4 acc[4][4];
#pragma unroll
    for (int i = 0; i < 4; ++i)
#pragma unroll
        for (int j = 0; j < 4; ++j) acc[i][j] = zero4;

    auto stage = [&](int t, int s) {
        int k0 = t * 32;
        int ao = s * 4096 + (w * 32) * 32;
        int bo = 12288 + s * 4096 + (w * 32) * 32;
        gl2lds16(aptr + k0, smem + ao);
        gl2lds16(aptr + (size_t)16 * K + k0, smem + ao + 16 * 32);
        gl2lds16(bptr + k0, smem + bo);
        gl2lds16(bptr + (size_t)16 * K + k0, smem + bo + 16 * 32);
    };

    stage(0, 0);
    stage(1, 1);
    int cur = 0;
    for (int t = 0; t < NT; ++t) {
        if (t < NT - 1) asm volatile("s_waitcnt vmcnt(4)" ::: "memory");
        else            asm volatile("s_waitcnt vmcnt(0)" ::: "memory");
        asm volatile("s_barrier" ::: "memory");
        if (t + 2 < NT) {
            int nxt = cur + 2; if (nxt >= 3) nxt -= 3;
            stage(t + 2, nxt);
        }
        const _Float16* Asr = smem + cur * 4096;
        const _Float16* Bsr = smem + 12288 + cur * 4096;
        f16x8 af[4], bf[4];
#pragma unroll
        for (int i = 0; i < 4; ++i)
            af[i] = *(const f16x8*)&Asr[(wm * 64 + i * 16 + m16) * 32 + acol];
#pragma unroll
        for (int j = 0; j < 4; ++j)
            bf[j] = *(const f16x8*)&Bsr[(wn * 64 + j * 16 + m16) * 32 + acol];
#pragma unroll
        for (int i = 0; i < 4; ++i)
#pragma unroll
            for (int j = 0; j < 4; ++j)
                acc[i][j] = MFMA16(af[i], bf[j], acc[i][j]);
        cur = (cur == 2) ? 0 : cur + 1;
    }

    // ---- epilogue: bias (+scale for Q), LDS bounce, coalesced stores ----
    int which = n0 >> 10;                     // 0=Q 1=K 2=V (block is pure)
    const float* bias = (which == 0) ? bias0 : (which == 1) ? bias1 : bias2;
    __syncthreads();
#pragma unroll
    for (int j = 0; j < 4; ++j) {
        int n_local = wn * 64 + j * 16 + m16;
        float bi = bias[(n0 + n_local) & 1023];
#pragma unroll
        for (int i = 0; i < 4; ++i)
#pragma unroll
            for (int r = 0; r < 4; ++r) {
                int m_local = wm * 64 + i * 16 + quad * 4 + r;
                float v = acc[i][j][r] + bi;
                if (which == 0) v *= 0.18033688011112042f;  // (1/sqrt(64))*log2(e)
                if (which == 2) smem[n_local * 132 + m_local] = (_Float16)v;   // transposed
                else            smem[m_local * 132 + n_local] = (_Float16)v;
            }
    }
    __syncthreads();

    int b = row0 >> 11, s0 = row0 & 2047;
    if (which == 2) {
#pragma unroll
        for (int p = 0; p < 8; ++p) {
            int n_local = p * 16 + (tid >> 4);
            int schunk = tid & 15;
            f16x8 v = *(const f16x8*)&smem[n_local * 132 + schunk * 8];
            int nw = (n0 + n_local) & 1023;
            int hh = nw >> 6, d = nw & 63;
            *(f16x8*)&Vt[((size_t)(b * NHH + hh) * HDD + d) * SS + s0 + schunk * 8] = v;
        }
    } else {
        _Float16* dst = (which == 0) ? Qh : Kh;
        int hh0 = (n0 & 1023) >> 6;
#pragma unroll
        for (int p = 0; p < 8; ++p) {
            int m_local = p * 16 + (tid >> 4);
            int seg = tid & 15;
            f16x8 v = *(const f16x8*)&smem[m_local * 132 + seg * 8];
            int hh = hh0 + (seg >> 3), d = (seg & 7) * 8;
            *(f16x8*)&dst[((size_t)(b * NHH + hh) * SS + s0 + m_local) * HDD + d] = v;
        }
    }
}

// ---------------- Output projection: 128x128 tile, split-K=2, atomic f32 epilogue -------
// Old version: grid 256 = 1 block/CU = 1 wave/SIMD — fully exposed latency (~25us for
// 14.5us of MFMA-limited work). Split K into 2x512: grid (8,32,2)=512 blocks = 2/CU,
// SAME MFMA-per-phase (R3 showed halving that is a loss), half the iterations per block.
// Output pre-zeroed by prep z==5; slice 0 folds the bias; both slices atomicAdd.
__global__ __launch_bounds__(256) void gemm_out_kernel(
    const _Float16* __restrict__ A, const _Float16* __restrict__ Bt,
    const float* __restrict__ bias0, float* __restrict__ Out)
{
    const int K = HH;
    const int NT = 16;                        // 512 of K per slice
    __shared__ _Float16 smem[24576];          // 49152 B: 3-stage bufs

    int row0 = blockIdx.y * 128, n0 = blockIdx.x * 128;
    int kbase = blockIdx.z * 512;
    int tid = threadIdx.x;
    int w = tid >> 6, l = tid & 63, m16 = l & 15, quad = l >> 4;
    int wm = w >> 1, wn = w & 1;

    int srow = w * 32 + (l >> 2);
    int sch = (l & 3) ^ ((l >> 2) & 3) ^ ((l >> 4) & 3);
    const _Float16* aptr = A + (size_t)(row0 + srow) * K + kbase + sch * 8;
    const _Float16* bptr = Bt + (size_t)(n0 + srow) * K + kbase + sch * 8;

    int gsw = (m16 & 3) ^ ((m16 >> 2) & 3);
    int acol = (quad ^ gsw) * 8;

    f32x4 zero4 = {0.f, 0.f, 0.f, 0.f};
    f32x4 acc[4][4];
#pragma unroll
    for (int i = 0; i < 4; ++i)
#pragma unroll
        for (int j = 0; j < 4; ++j) acc[i][j] = zero4;

    auto stage = [&](int t, int s) {
        int k0 = t * 32;
        int ao = s * 4096 + (w * 32) * 32;
        int bo = 12288 + s * 4096 + (w * 32) * 32;
        gl2lds16(aptr + k0, smem + ao);
        gl2lds16(aptr + (size_t)16 * K + k0, smem + ao + 16 * 32);
        gl2lds16(bptr + k0, smem + bo);
        gl2lds16(bptr + (size_t)16 * K + k0, smem + bo + 16 * 32);
    };

    stage(0, 0);
    stage(1, 1);
    int cur = 0;
    for (int t = 0; t < NT; ++t) {
        if (t < NT - 1) asm volatile("s_waitcnt vmcnt(4)" ::: "memory");
        else            asm volatile("s_waitcnt vmcnt(0)" ::: "memory");
        asm volatile("s_barrier" ::: "memory");
        if (t + 2 < NT) {
            int nxt = cur + 2; if (nxt >= 3) nxt -= 3;
            stage(t + 2, nxt);
        }
        const _Float16* Asr = smem + cur * 4096;
        const _Float16* Bsr = smem + 12288 + cur * 4096;
        f16x8 af[4], bf[4];
#pragma unroll
        for (int i = 0; i < 4; ++i)
            af[i] = *(const f16x8*)&Asr[(wm * 64 + i * 16 + m16) * 32 + acol];
#pragma unroll
        for (int j = 0; j < 4; ++j)
            bf[j] = *(const f16x8*)&Bsr[(wn * 64 + j * 16 + m16) * 32 + acol];
#pragma unroll
        for (int i = 0; i < 4; ++i)
#pragma unroll
            for (int j = 0; j < 4; ++j)
                acc[i][j] = MFMA16(af[i], bf[j], acc[i][j]);
        cur = (cur == 2) ? 0 : cur + 1;
    }

    bool addb = (blockIdx.z == 0);
#pragma unroll
    for (int j = 0; j < 4; ++j) {
        int n = n0 + wn * 64 + j * 16 + m16;
        float bi = addb ? bias0[n] : 0.f;
#pragma unroll
        for (int i = 0; i < 4; ++i)
#pragma unroll
            for (int r = 0; r < 4; ++r) {
                int mg = row0 + wm * 64 + i * 16 + quad * 4 + r;
                atomicAdd(&Out[(size_t)mg * HH + n], acc[i][j][r] + bi);
            }
    }
}

// ---------------- Flash attention: S^T, 8-wave KV-parity split, paired q-tiles ----------
// grid (16, NH, B), block 512 (8 waves). Every wave holds BOTH q-tiles' state
// (tA=bx, tB=31-tA — R0's proven 84-VGPR register profile); wave-group g = w>>2
// processes KV-tiles of parity g for BOTH tiles. vs the idle-half design: 100% wave
// body-density and iterations drop 32 -> <=17; K/V frags loaded once per iter feed
// 2 bodies. Partial (o, lacc) are pure sums (no running max) so the parity split is
// exactly associative; cross-group combine via one LDS exchange at the end.
// Staging: tile-PAIRS into a 64KB double buffer with the proven two-barrier +
// counted-vmcnt(4) pattern (4 gl2lds16 per wave per pair).
__global__ __launch_bounds__(512, 4) void attn_kernel(
    const _Float16* __restrict__ Qh, const _Float16* __restrict__ Kh,
    const _Float16* __restrict__ Vt, _Float16* __restrict__ Ctx)
{
    __shared__ _Float16 KV[32768];        // 65536 B: 2 pair-bufs x {K_e,V_e,K_o,V_o} x 8KB

    int tid = threadIdx.x;
    int w = tid >> 6, l = tid & 63;
    int m16 = l & 15, quad = l >> 4;
    int b = blockIdx.z, h = blockIdx.y;
    int tA = blockIdx.x, tB = 31 - tA;    // tA in [0,15], tB in [16,31]
    int g = w >> 2, wq = w & 3;           // KV parity group, q-sub-row

    const _Float16* Q = Qh + (size_t)(b * NHH + h) * SS * HDD;
    const _Float16* K = Kh + (size_t)(b * NHH + h) * SS * HDD;
    const _Float16* V = Vt + (size_t)(b * NHH + h) * HDD * SS;

    int qA = tA * 64 + wq * 16 + m16;
    int qB = tB * 64 + wq * 16 + m16;
    f16x8 aqA0 = *(const f16x8*)(Q + (size_t)qA * HDD + quad * 8);
    f16x8 aqA1 = *(const f16x8*)(Q + (size_t)qA * HDD + 32 + quad * 8);
    f16x8 aqB0 = *(const f16x8*)(Q + (size_t)qB * HDD + quad * 8);
    f16x8 aqB1 = *(const f16x8*)(Q + (size_t)qB * HDD + 32 + quad * 8);

    // staging: wave w covers rows [w*8, w*8+8) of each {K,V} x {even,odd}
    int srow = w * 8 + (l >> 3);
    int sch = (l & 7) ^ (l >> 3);
    const _Float16* kg = K + (size_t)srow * HDD + sch * 8;
    const _Float16* vg = V + (size_t)srow * SS + sch * 8;

    auto stage_pair = [&](int p) {        // stages tiles 2p, 2p+1 into buf[p&1]
        _Float16* base = &KV[(p & 1) * 16384];
        int t0 = p * 128;                 // row/col offset of tile 2p
        gl2lds16(kg + (size_t)t0 * HDD,        base + (w * 8) * 64);
        gl2lds16(vg + t0,                      base + 4096 + (w * 8) * 64);
        gl2lds16(kg + (size_t)(t0 + 64) * HDD, base + 8192 + (w * 8) * 64);
        gl2lds16(vg + t0 + 64,                 base + 12288 + (w * 8) * 64);
    };

    int swz = m16 & 7;
    int cka = (quad ^ swz) * 8;          // K-frag d-chunk 0..31
    int ckb = ((quad + 4) ^ swz) * 8;    // K-frag d-chunk 32..63
    int vco[4];
#pragma unroll
    for (int s = 0; s < 4; ++s)
        vco[s] = (((s * 2 + (quad >> 1)) ^ swz) * 8) + (quad & 1) * 4;

    f32x4 zero4 = {0.f, 0.f, 0.f, 0.f};
    const f16x4 ones4 = {(_Float16)1.f, (_Float16)1.f, (_Float16)1.f, (_Float16)1.f};
    f32x4 oA[4], oB[4];                  // O^T partials: row d=c*16+quad*4+r, col q=m16
#pragma unroll
    for (int c = 0; c < 4; ++c) { oA[c] = zero4; oB[c] = zero4; }
    f32x4 laccA = zero4, laccB = zero4;  // denominator partials (rows identical)

    int NIT = (tB >> 1) + 1;
    stage_pair(0);
    for (int it = 0; it < NIT; ++it) {
        // barrier#1: all waves done reading buf[(it+1)&1] (last used at it-1)
        asm volatile("s_barrier" ::: "memory");
        if (2 * (it + 1) <= tB) {
            stage_pair(it + 1);
            asm volatile("s_waitcnt vmcnt(4)" ::: "memory");   // pair-it certified
        } else {
            asm volatile("s_waitcnt vmcnt(0)" ::: "memory");
        }
        asm volatile("s_barrier" ::: "memory");  // barrier#2: pair-it visible to all

        int t = 2 * it + g;               // this group's KV-tile (wave-uniform)
        if (t <= tB) {
            int kt = t * 64;
            const _Float16* kb = &KV[(it & 1) * 16384 + g * 8192];
            const _Float16* vb = kb + 4096;
            f16x8 bk[4][2];
#pragma unroll
            for (int s = 0; s < 4; ++s) {
                const _Float16* kr = kb + (s * 16 + m16) * 64;
                bk[s][0] = *(const f16x8*)(kr + cka);
                bk[s][1] = *(const f16x8*)(kr + ckb);
            }
            f16x4 av[4][4];
#pragma unroll
            for (int c = 0; c < 4; ++c) {
                const _Float16* vr = vb + (c * 16 + m16) * 64;
#pragma unroll
                for (int s = 0; s < 4; ++s)
                    av[c][s] = *(const f16x4*)(vr + vco[s]);
            }

            auto body = [&](const f16x8& q0, const f16x8& q1, int qlane,
                            f32x4* o, f32x4& lacc, bool masked) {
                f32x4 st[4];
#pragma unroll
                for (int s = 0; s < 4; ++s) {
                    st[s] = MFMA16(bk[s][0], q0, zero4);
                    st[s] = MFMA16(bk[s][1], q1, st[s]);
                }
                f16x4 pt[4];
#pragma unroll
                for (int s = 0; s < 4; ++s) {
#pragma unroll
                    for (int r = 0; r < 4; ++r) {
                        float p = fexp2(st[s][r]);
                        if (masked) {
                            int key = kt + s * 16 + quad * 4 + r;
                            if (key > qlane) p = 0.f;
                        }
                        pt[s][r] = (_Float16)p;
                    }
                    lacc = MFMA16K16(ones4, pt[s], lacc);
                }
#pragma unroll
                for (int c = 0; c < 4; ++c)
#pragma unroll
                    for (int s = 0; s < 4; ++s)
                        o[c] = MFMA16K16(av[c][s], pt[s], o[c]);
            };

            body(aqB0, aqB1, qB, oB, laccB, t == tB);
            if (t <= tA) body(aqA0, aqA1, qA, oA, laccA, t == tA);
        }
    }

    // ---- cross-group combine via LDS (KV reused): wave w finalizes tile (g?B:A) ----
    float* ox = (float*)KV;               // [8 waves][64 lanes][16] f32 = 32 KB
    float* lx = (float*)&KV[16384];       // [8][64] f32 = 2 KB
    __syncthreads();
    f32x4* slot = (f32x4*)(ox + ((w * 64 + l) * 16));
#pragma unroll
    for (int c = 0; c < 4; ++c) slot[c] = g ? oA[c] : oB[c];   // write OTHER tile's partial
    lx[w * 64 + l] = g ? laccA[0] : laccB[0];
    __syncthreads();
    int pw = w ^ 4;                       // partner wave (other group, same wq)
    const f32x4* pslot = (const f32x4*)(ox + ((pw * 64 + l) * 16));
    f32x4 of[4];
#pragma unroll
    for (int c = 0; c < 4; ++c) of[c] = (g ? oB[c] : oA[c]) + pslot[c];
    float lf = (g ? laccB[0] : laccA[0]) + lx[pw * 64 + l];

    int q = g ? qB : qA;
    float inv = 1.0f / lf;
    size_t rowoff = ((size_t)(b * SS) + q) * HH + h * HDD;
#pragma unroll
    for (int c = 0; c < 4; ++c) {
        f16x4 ov;
#pragma unroll
        for (int r = 0; r < 4; ++r) ov[r] = (_Float16)(of[c][r] * inv);
        *(f16x4*)&Ctx[rowoff + c * 16 + quad * 4] = ov;
    }
}

extern "C" void kernel_launch(void* const* d_in, const int* in_sizes, int n_in,
                              void* d_out, int out_size, void* d_ws, size_t ws_size,
                              hipStream_t stream) {
    const float* hs = (const float*)d_in[0];
    const float* Wq = (const float*)d_in[1];
    const float* bq = (const float*)d_in[2];
    const float* Wk = (const float*)d_in[3];
    const float* bk = (const float*)d_in[4];
    const float* Wv = (const float*)d_in[5];
    const float* bv = (const float*)d_in[6];
    const float* Wo = (const float*)d_in[7];
    const float* bo = (const float*)d_in[8];
    float* out = (float*)d_out;

    size_t off = 0;
    auto alloc = [&](size_t bytes) {
        void* p = (char*)d_ws + off;
        off += (bytes + 255) & ~(size_t)255;
        return p;
    };
    _Float16* Xh    = (_Float16*)alloc((size_t)MM * HH * 2);
    _Float16* WqkvT = (_Float16*)alloc((size_t)3 * HH * HH * 2);
    _Float16* WoT   = (_Float16*)alloc((size_t)HH * HH * 2);
    _Float16* Qh    = (_Float16*)alloc((size_t)BB * NHH * SS * HDD * 2);
    _Float16* Kh    = (_Float16*)alloc((size_t)BB * NHH * SS * HDD * 2);
    _Float16* Vt    = (_Float16*)alloc((size_t)BB * NHH * SS * HDD * 2);
    _Float16* Ctx   = (_Float16*)alloc((size_t)MM * HH * 2);

    prep_kernel<<<dim3(16, 16, 6), 256, 0, stream>>>(
        hs, Wq, Wk, Wv, Wo, Xh, WqkvT, WoT, out);
    gemm_qkv_kernel<<<dim3(QKV_N / 128, MM / 128), 256, 0, stream>>>(
        Xh, WqkvT, bq, bk, bv, Qh, Kh, Vt);
    attn_kernel<<<dim3(16, NHH, BB), 512, 0, stream>>>(Qh, Kh, Vt, Ctx);
    gemm_out_kernel<<<dim3(HH / 128, MM / 128, 2), 256, 0, stream>>>(
        Ctx, WoT, bo, out);
}

// Round 7
// 185.157 us; speedup vs baseline: 1.3557x; 1.3557x over previous
//
#include <hip/hip_runtime.h>
#include <hip/hip_bf16.h>

// Problem constants
#define BB 2
#define SS 2048
#define HH 1024
#define NHH 16
#define HDD 64
#define MM (BB*SS)        // 4096
#define QKV_N (3*HH)      // 3072

typedef _Float16 f16x8 __attribute__((ext_vector_type(8)));
typedef _Float16 f16x4 __attribute__((ext_vector_type(4)));
typedef float f32x4 __attribute__((ext_vector_type(4)));

#define MFMA16(a,b,c)  __builtin_amdgcn_mfma_f32_16x16x32_f16((a),(b),(c),0,0,0)
#define MFMA16K16(a,b,c) __builtin_amdgcn_mfma_f32_16x16x16f16((a),(b),(c),0,0,0)

// async global->LDS 16B per lane; LDS dest = wave-uniform base + lane*16
__device__ __forceinline__ void gl2lds16(const _Float16* g, _Float16* l) {
    __builtin_amdgcn_global_load_lds(
        (const __attribute__((address_space(1))) void*)g,
        (__attribute__((address_space(3))) void*)l, 16, 0, 0);
}

// single-instruction exp2 WITH compiler hazard handling (raw asm broke TRANS-op waits)
__device__ __forceinline__ float fexp2(float x) { return __builtin_amdgcn_exp2f(x); }

// ---------------- prep: z<4 transpose-cast W -> Wt fp16; z==4 cast X -> fp16 ------------
// grid (16,16,5), block 256.
__global__ __launch_bounds__(256) void prep_kernel(
    const float* __restrict__ X,
    const float* __restrict__ W0, const float* __restrict__ W1,
    const float* __restrict__ W2, const float* __restrict__ W3,
    _Float16* __restrict__ Xh,
    _Float16* __restrict__ WqkvT, _Float16* __restrict__ WoT)
{
    __shared__ float t[64][65];
    int z = blockIdx.z;
    int tid = threadIdx.x;
    if (z == 4) {
        int base = (blockIdx.y * 16 + blockIdx.x) * 256 + tid;
        const float4* xin = (const float4*)X;
        f16x4* xout = (f16x4*)Xh;
#pragma unroll
        for (int i = 0; i < 16; ++i) {
            float4 v = xin[base + i * 65536];
            f16x4 hh = {(_Float16)v.x, (_Float16)v.y, (_Float16)v.z, (_Float16)v.w};
            xout[base + i * 65536] = hh;
        }
        return;
    }
    const float* src = (z == 0) ? W0 : (z == 1) ? W1 : (z == 2) ? W2 : W3;
    _Float16* dst = (z < 3) ? (WqkvT + (size_t)z * HH * HH) : WoT;
    int k0 = blockIdx.y * 64, n0 = blockIdx.x * 64;
#pragma unroll
    for (int p = 0; p < 4; ++p) {
        int row = p * 16 + (tid >> 4);
        int col4 = (tid & 15) * 4;
        float4 v = *(const float4*)&src[(size_t)(k0 + row) * HH + n0 + col4];
        t[row][col4 + 0] = v.x; t[row][col4 + 1] = v.y;
        t[row][col4 + 2] = v.z; t[row][col4 + 3] = v.w;
    }
    __syncthreads();
#pragma unroll
    for (int p = 0; p < 2; ++p) {
        int nc = p * 32 + (tid >> 3);
        int ch = tid & 7;
        f16x8 o;
#pragma unroll
        for (int j = 0; j < 8; ++j) o[j] = (_Float16)t[ch * 8 + j][nc];
        *(f16x8*)&dst[(size_t)(n0 + nc) * HH + k0 + ch * 8] = o;
    }
}

// ---------------- QKV GEMM: 256x256 tile, 4-phase/K-step counted-vmcnt schedule ---------
// 8-phase-family port (current 128^2 3-stage = 593 TF = the 2-phase structural ceiling).
// BK=64 as 2x32 slabs (byte-identical proven swizzle algebra). 8 waves (2M x 4N),
// wave tile 128x64, acc[8][4]=128 VGPR. LDS 128KB: per-K-step double buffer
// A[buf][ks][256][32] + B same. While K-step s is read (4 phases = quadrants
// (m0n0)(m0n1)(m1n1)(m1n0), 16 MFMA each, setprio-wrapped), the free buffer receives
// s+1's 4 half-tiles, 1/phase (2 loads/wave). vmcnt(2) ONCE per K-step at phase 1
// (certifies s's 8 loads, keeps 2 newest in flight — never drains mid-loop).
// Barriers: 1/phase end; phase-4's is the correctness fence (reads of buf drained
// before next K-step's stage overwrites it); +1 after the phase-1 vmcnt (visibility).
__global__ __launch_bounds__(512, 2) void gemm_qkv_kernel(
    const _Float16* __restrict__ A, const _Float16* __restrict__ Bt,
    const float* __restrict__ bias0, const float* __restrict__ bias1, const float* __restrict__ bias2,
    _Float16* __restrict__ Qh, _Float16* __restrict__ Kh, _Float16* __restrict__ Vt)
{
    __shared__ _Float16 smem[65536];      // 128 KiB

    // bijective XCD swizzle: 192 blocks = 24/XCD exactly
    int bid = blockIdx.y * 12 + blockIdx.x;
    int swzb = (bid & 7) * 24 + (bid >> 3);
    int bx = swzb % 12, by = swzb / 12;
    int row0 = by * 256, n0 = bx * 256;

    int tid = threadIdx.x;
    int w = tid >> 6, l = tid & 63, m16 = l & 15, quad = l >> 4;
    int wm = w >> 2, wn = w & 3;          // wave tile: rows wm*128, cols wn*64

    // staging: per instr wave w covers 16 rows x 64B of one 32-f16 slab
    int srow = w * 16 + (l >> 2);         // lane row within 128-row half
    int sch = (l & 3) ^ ((l >> 2) & 3) ^ ((l >> 4) & 3);
    const _Float16* aptr = A + (size_t)(row0 + srow) * HH + sch * 8;
    const _Float16* bptr = Bt + (size_t)(n0 + srow) * HH + sch * 8;

    int gsw = (m16 & 3) ^ ((m16 >> 2) & 3);
    int acol = (quad ^ gsw) * 8;

    f32x4 zero4 = {0.f, 0.f, 0.f, 0.f};
    f32x4 acc[8][4];
#pragma unroll
    for (int i = 0; i < 8; ++i)
#pragma unroll
        for (int j = 0; j < 4; ++j) acc[i][j] = zero4;

    // LDS (f16 units): A [buf][ks][256][32] at buf*16384 + ks*8192; B at +32768.
    auto stageA = [&](int s, int h, int ks) {
        gl2lds16(aptr + (size_t)h * 128 * HH + s * 64 + ks * 32,
                 smem + (s & 1) * 16384 + ks * 8192 + (h * 128 + w * 16) * 32);
    };
    auto stageB = [&](int s, int h, int ks) {
        gl2lds16(bptr + (size_t)h * 128 * HH + s * 64 + ks * 32,
                 smem + 32768 + (s & 1) * 16384 + ks * 8192 + (h * 128 + w * 16) * 32);
    };

    // prologue: all 4 half-tiles of K-step 0 (8 loads/wave)
    stageA(0, 0, 0); stageA(0, 0, 1); stageA(0, 1, 0); stageA(0, 1, 1);
    stageB(0, 0, 0); stageB(0, 0, 1); stageB(0, 1, 0); stageB(0, 1, 1);

    for (int s = 0; s < 16; ++s) {
        const _Float16* Ab = smem + (s & 1) * 16384;
        const _Float16* Bb = smem + 32768 + (s & 1) * 16384;
        bool pf = (s + 1 < 16);
        f16x8 af[4][2], bf[2][2];

        // ---- phase 1: quadrant (m0, n0); stage A(s+1) h0; counted vmcnt ----
        if (pf) { stageA(s + 1, 0, 0); stageA(s + 1, 0, 1);
                  asm volatile("s_waitcnt vmcnt(2)" ::: "memory"); }
        else    { asm volatile("s_waitcnt vmcnt(0)" ::: "memory"); }
        asm volatile("s_barrier" ::: "memory");
#pragma unroll
        for (int fi = 0; fi < 4; ++fi)
#pragma unroll
            for (int ks = 0; ks < 2; ++ks)
                af[fi][ks] = *(const f16x8*)&Ab[ks * 8192 + (wm * 128 + fi * 16 + m16) * 32 + acol];
#pragma unroll
        for (int fj = 0; fj < 2; ++fj)
#pragma unroll
            for (int ks = 0; ks < 2; ++ks)
                bf[fj][ks] = *(const f16x8*)&Bb[ks * 8192 + (wn * 64 + fj * 16 + m16) * 32 + acol];
        __builtin_amdgcn_s_setprio(1);
#pragma unroll
        for (int fi = 0; fi < 4; ++fi)
#pragma unroll
            for (int fj = 0; fj < 2; ++fj) {
                acc[fi][fj] = MFMA16(af[fi][0], bf[fj][0], acc[fi][fj]);
                acc[fi][fj] = MFMA16(af[fi][1], bf[fj][1], acc[fi][fj]);
            }
        __builtin_amdgcn_s_setprio(0);
        asm volatile("s_barrier" ::: "memory");

        // ---- phase 2: quadrant (m0, n1); stage A(s+1) h1 ----
        if (pf) { stageA(s + 1, 1, 0); stageA(s + 1, 1, 1); }
#pragma unroll
        for (int fj = 0; fj < 2; ++fj)
#pragma unroll
            for (int ks = 0; ks < 2; ++ks)
                bf[fj][ks] = *(const f16x8*)&Bb[ks * 8192 + (wn * 64 + 32 + fj * 16 + m16) * 32 + acol];
        __builtin_amdgcn_s_setprio(1);
#pragma unroll
        for (int fi = 0; fi < 4; ++fi)
#pragma unroll
            for (int fj = 0; fj < 2; ++fj) {
                acc[fi][2 + fj] = MFMA16(af[fi][0], bf[fj][0], acc[fi][2 + fj]);
                acc[fi][2 + fj] = MFMA16(af[fi][1], bf[fj][1], acc[fi][2 + fj]);
            }
        __builtin_amdgcn_s_setprio(0);
        asm volatile("s_barrier" ::: "memory");

        // ---- phase 3: quadrant (m1, n1); stage B(s+1) h0 ----
        if (pf) { stageB(s + 1, 0, 0); stageB(s + 1, 0, 1); }
#pragma unroll
        for (int fi = 0; fi < 4; ++fi)
#pragma unroll
            for (int ks = 0; ks < 2; ++ks)
                af[fi][ks] = *(const f16x8*)&Ab[ks * 8192 + (wm * 128 + 64 + fi * 16 + m16) * 32 + acol];
        __builtin_amdgcn_s_setprio(1);
#pragma unroll
        for (int fi = 0; fi < 4; ++fi)
#pragma unroll
            for (int fj = 0; fj < 2; ++fj) {
                acc[4 + fi][2 + fj] = MFMA16(af[fi][0], bf[fj][0], acc[4 + fi][2 + fj]);
                acc[4 + fi][2 + fj] = MFMA16(af[fi][1], bf[fj][1], acc[4 + fi][2 + fj]);
            }
        __builtin_amdgcn_s_setprio(0);
        asm volatile("s_barrier" ::: "memory");

        // ---- phase 4: quadrant (m1, n0); stage B(s+1) h1 ----
        if (pf) { stageB(s + 1, 1, 0); stageB(s + 1, 1, 1); }
#pragma unroll
        for (int fj = 0; fj < 2; ++fj)
#pragma unroll
            for (int ks = 0; ks < 2; ++ks)
                bf[fj][ks] = *(const f16x8*)&Bb[ks * 8192 + (wn * 64 + fj * 16 + m16) * 32 + acol];
        __builtin_amdgcn_s_setprio(1);
#pragma unroll
        for (int fi = 0; fi < 4; ++fi)
#pragma unroll
            for (int fj = 0; fj < 2; ++fj) {
                acc[4 + fi][fj] = MFMA16(af[fi][0], bf[fj][0], acc[4 + fi][fj]);
                acc[4 + fi][fj] = MFMA16(af[fi][1], bf[fj][1], acc[4 + fi][fj]);
            }
        __builtin_amdgcn_s_setprio(0);
        asm volatile("s_barrier" ::: "memory");   // fence: buf reads done before next stage
    }

    // ---- epilogue: bias (+scale Q), 2 half passes of 128 rows via LDS bounce ----
    int which = n0 >> 10;                 // 0=Q 1=K 2=V (256 | 1024 -> block-pure)
    const float* bias = (which == 0) ? bias0 : (which == 1) ? bias1 : bias2;
    int b = row0 >> 11, s0 = row0 & 2047;

#pragma unroll
    for (int rh = 0; rh < 2; ++rh) {
        __syncthreads();
        if (wm == rh) {
#pragma unroll
            for (int j = 0; j < 4; ++j) {
                int n_local = wn * 64 + j * 16 + m16;
                float bi = bias[(n0 + n_local) & 1023];
#pragma unroll
                for (int i = 0; i < 8; ++i)
#pragma unroll
                    for (int r = 0; r < 4; ++r) {
                        int m_loc = i * 16 + quad * 4 + r;          // 0..127 within half
                        float v = acc[i][j][r] + bi;
                        if (which == 0) v *= 0.18033688011112042f;  // (1/sqrt(64))*log2(e)
                        if (which == 2) smem[n_local * 136 + m_loc] = (_Float16)v;  // [n256][s128+8]
                        else            smem[m_loc * 264 + n_local] = (_Float16)v;  // [s128][n256+8]
                    }
            }
        }
        __syncthreads();
        int hs0 = s0 + rh * 128;
        if (which == 2) {
#pragma unroll
            for (int p = 0; p < 8; ++p) {
                int n_local = p * 32 + (tid >> 4);
                int schunk = tid & 15;
                f16x8 v = *(const f16x8*)&smem[n_local * 136 + schunk * 8];
                int nw = (n0 + n_local) & 1023;
                int hh = nw >> 6, d = nw & 63;
                *(f16x8*)&Vt[((size_t)(b * NHH + hh) * HDD + d) * SS + hs0 + schunk * 8] = v;
            }
        } else {
            _Float16* dst = (which == 0) ? Qh : Kh;
            int hh0 = (n0 & 1023) >> 6;
#pragma unroll
            for (int p = 0; p < 8; ++p) {
                int m_local = p * 16 + (tid >> 5);
                int seg = tid & 31;
                f16x8 v = *(const f16x8*)&smem[m_local * 264 + seg * 8];
                int hh = hh0 + (seg >> 3), d = (seg & 7) * 8;
                *(f16x8*)&dst[((size_t)(b * NHH + hh) * SS + hs0 + m_local) * HDD + d] = v;
            }
        }
    }
}

// ---------------- Output projection: 128x128 tile, 3-stage, direct fp32 store -----------
// (proven R1 version: split-K atomic variant cost ~+10us, reverted)
__global__ __launch_bounds__(256) void gemm_out_kernel(
    const _Float16* __restrict__ A, const _Float16* __restrict__ Bt,
    const float* __restrict__ bias0, float* __restrict__ Out)
{
    const int K = HH;
    const int NT = K / 32;
    __shared__ _Float16 smem[24576];          // 49152 B: 3-stage bufs

    int row0 = blockIdx.y * 128, n0 = blockIdx.x * 128;
    int tid = threadIdx.x;
    int w = tid >> 6, l = tid & 63, m16 = l & 15, quad = l >> 4;
    int wm = w >> 1, wn = w & 1;

    int srow = w * 32 + (l >> 2);
    int sch = (l & 3) ^ ((l >> 2) & 3) ^ ((l >> 4) & 3);
    const _Float16* aptr = A + (size_t)(row0 + srow) * K + sch * 8;
    const _Float16* bptr = Bt + (size_t)(n0 + srow) * K + sch * 8;

    int gsw = (m16 & 3) ^ ((m16 >> 2) & 3);
    int acol = (quad ^ gsw) * 8;

    f32x4 zero4 = {0.f, 0.f, 0.f, 0.f};
    f32x4 acc[4][4];
#pragma unroll
    for (int i = 0; i < 4; ++i)
#pragma unroll
        for (int j = 0; j < 4; ++j) acc[i][j] = zero4;

    auto stage = [&](int t, int s) {
        int k0 = t * 32;
        int ao = s * 4096 + (w * 32) * 32;
        int bo = 12288 + s * 4096 + (w * 32) * 32;
        gl2lds16(aptr + k0, smem + ao);
        gl2lds16(aptr + (size_t)16 * K + k0, smem + ao + 16 * 32);
        gl2lds16(bptr + k0, smem + bo);
        gl2lds16(bptr + (size_t)16 * K + k0, smem + bo + 16 * 32);
    };

    stage(0, 0);
    stage(1, 1);
    int cur = 0;
    for (int t = 0; t < NT; ++t) {
        if (t < NT - 1) asm volatile("s_waitcnt vmcnt(4)" ::: "memory");
        else            asm volatile("s_waitcnt vmcnt(0)" ::: "memory");
        asm volatile("s_barrier" ::: "memory");
        if (t + 2 < NT) {
            int nxt = cur + 2; if (nxt >= 3) nxt -= 3;
            stage(t + 2, nxt);
        }
        const _Float16* Asr = smem + cur * 4096;
        const _Float16* Bsr = smem + 12288 + cur * 4096;
        f16x8 af[4], bf[4];
#pragma unroll
        for (int i = 0; i < 4; ++i)
            af[i] = *(const f16x8*)&Asr[(wm * 64 + i * 16 + m16) * 32 + acol];
#pragma unroll
        for (int j = 0; j < 4; ++j)
            bf[j] = *(const f16x8*)&Bsr[(wn * 64 + j * 16 + m16) * 32 + acol];
#pragma unroll
        for (int i = 0; i < 4; ++i)
#pragma unroll
            for (int j = 0; j < 4; ++j)
                acc[i][j] = MFMA16(af[i], bf[j], acc[i][j]);
        cur = (cur == 2) ? 0 : cur + 1;
    }

#pragma unroll
    for (int j = 0; j < 4; ++j) {
        int n = n0 + wn * 64 + j * 16 + m16;
        float bi = bias0[n];
#pragma unroll
        for (int i = 0; i < 4; ++i)
#pragma unroll
            for (int r = 0; r < 4; ++r) {
                int mg = row0 + wm * 64 + i * 16 + quad * 4 + r;
                Out[(size_t)mg * HH + n] = acc[i][j][r] + bi;
            }
    }
}

// ---------------- Flash attention: S^T formulation, 8-wave tile-split (proven ~32us) ----
// grid (16, NH, B), block 512 (8 waves). Waves 0-3 own q-tile tA=bx, waves 4-7 own
// tB=31-tA. (KV-parity experiment reverted: dual-tile state spilled to scratch —
// FETCH/WRITE exploded to 180/117 MB, 90us.)
__global__ __launch_bounds__(512, 4) void attn_kernel(
    const _Float16* __restrict__ Qh, const _Float16* __restrict__ Kh,
    const _Float16* __restrict__ Vt, _Float16* __restrict__ Ctx)
{
    __shared__ _Float16 KV[3 * 8192];     // 49152 B, 3-stage K+V

    int tid = threadIdx.x;
    int w = tid >> 6, l = tid & 63;
    int m16 = l & 15, quad = l >> 4;
    int b = blockIdx.z, h = blockIdx.y;
    int tA = blockIdx.x, tB = 31 - tA;
    int half = w >> 2, wq = w & 3;
    int myT = half ? tB : tA;             // this wave's q-tile index

    const _Float16* Q = Qh + (size_t)(b * NHH + h) * SS * HDD;
    const _Float16* K = Kh + (size_t)(b * NHH + h) * SS * HDD;
    const _Float16* V = Vt + (size_t)(b * NHH + h) * HDD * SS;

    int q = myT * 64 + wq * 16 + m16;     // this lane's q row (S^T: q = lane&15)
    f16x8 aq0 = *(const f16x8*)(Q + (size_t)q * HDD + quad * 8);
    f16x8 aq1 = *(const f16x8*)(Q + (size_t)q * HDD + 32 + quad * 8);

    // staging: wave w covers rows [w*8, w*8+8), one 8-row instr per matrix
    int srow = w * 8 + (l >> 3);
    int sch = (l & 7) ^ (l >> 3);
    const _Float16* kg = K + (size_t)srow * HDD + sch * 8;
    const _Float16* vg = V + (size_t)srow * SS + sch * 8;

    auto stage = [&](int t, int s) {
        int kt = t * 64;
        _Float16* kb = &KV[s * 8192];
        _Float16* vb = &KV[s * 8192 + 4096];
        gl2lds16(kg + (size_t)kt * HDD, kb + (w * 8) * 64);
        gl2lds16(vg + kt, vb + (w * 8) * 64);
    };

    int swz = m16 & 7;
    int cka = (quad ^ swz) * 8;          // K-frag d-chunk 0..31
    int ckb = ((quad + 4) ^ swz) * 8;    // K-frag d-chunk 32..63
    int vco[4];
#pragma unroll
    for (int s = 0; s < 4; ++s)
        vco[s] = (((s * 2 + (quad >> 1)) ^ swz) * 8) + (quad & 1) * 4;

    f32x4 zero4 = {0.f, 0.f, 0.f, 0.f};
    const f16x4 ones4 = {(_Float16)1.f, (_Float16)1.f, (_Float16)1.f, (_Float16)1.f};
    f32x4 o[4];                          // O^T: row d=c*16+quad*4+r, col q=m16
#pragma unroll
    for (int c = 0; c < 4; ++c) o[c] = zero4;
    f32x4 lacc = zero4;                  // softmax denominator (all rows identical)

    stage(0, 0);
    stage(1, 1);
    int cur = 0;
    for (int t = 0; t <= tB; ++t) {
        int kt = t * 64;
        if (t < tB) asm volatile("s_waitcnt vmcnt(2)" ::: "memory");
        else        asm volatile("s_waitcnt vmcnt(0)" ::: "memory");
        asm volatile("s_barrier" ::: "memory");
        if (t + 2 <= tB) {
            int nxt = cur + 2; if (nxt >= 3) nxt -= 3;
            stage(t + 2, nxt);
        }

        if (t <= myT) {                   // wave-uniform: body only while tile active
            const _Float16* kb = &KV[cur * 8192];
            const _Float16* vb = &KV[cur * 8192 + 4096];
            f16x8 bk[4][2];
#pragma unroll
            for (int s = 0; s < 4; ++s) {
                const _Float16* kr = kb + (s * 16 + m16) * 64;
                bk[s][0] = *(const f16x8*)(kr + cka);
                bk[s][1] = *(const f16x8*)(kr + ckb);
            }
            f16x4 av[4][4];              // [c d-block][s key-chunk]
#pragma unroll
            for (int c = 0; c < 4; ++c) {
                const _Float16* vr = vb + (c * 16 + m16) * 64;
#pragma unroll
                for (int s = 0; s < 4; ++s)
                    av[c][s] = *(const f16x4*)(vr + vco[s]);
            }

            f32x4 st[4];
#pragma unroll
            for (int s = 0; s < 4; ++s) {
                st[s] = MFMA16(bk[s][0], aq0, zero4);
                st[s] = MFMA16(bk[s][1], aq1, st[s]);
            }
            f16x4 pt[4];
            if (t == myT) {              // masked (diagonal) tile
#pragma unroll
                for (int s = 0; s < 4; ++s)
#pragma unroll
                    for (int r = 0; r < 4; ++r) {
                        float p = fexp2(st[s][r]);
                        int key = kt + s * 16 + quad * 4 + r;
                        if (key > q) p = 0.f;
                        pt[s][r] = (_Float16)p;
                    }
            } else {
#pragma unroll
                for (int s = 0; s < 4; ++s)
#pragma unroll
                    for (int r = 0; r < 4; ++r)
                        pt[s][r] = (_Float16)fexp2(st[s][r]);
            }
#pragma unroll
            for (int s = 0; s < 4; ++s)
                lacc = MFMA16K16(ones4, pt[s], lacc);
#pragma unroll
            for (int c = 0; c < 4; ++c)
#pragma unroll
                for (int s = 0; s < 4; ++s)
                    o[c] = MFMA16K16(av[c][s], pt[s], o[c]);
        }

        cur = (cur == 2) ? 0 : cur + 1;
    }

    // epilogue: normalize (denominator identical across rows/quads for a given q), store O^T
    float inv = 1.0f / lacc[0];
    size_t rowoff = ((size_t)(b * SS) + q) * HH + h * HDD;
#pragma unroll
    for (int c = 0; c < 4; ++c) {
        f16x4 ov;
#pragma unroll
        for (int r = 0; r < 4; ++r) ov[r] = (_Float16)(o[c][r] * inv);
        *(f16x4*)&Ctx[rowoff + c * 16 + quad * 4] = ov;
    }
}

extern "C" void kernel_launch(void* const* d_in, const int* in_sizes, int n_in,
                              void* d_out, int out_size, void* d_ws, size_t ws_size,
                              hipStream_t stream) {
    const float* hs = (const float*)d_in[0];
    const float* Wq = (const float*)d_in[1];
    const float* bq = (const float*)d_in[2];
    const float* Wk = (const float*)d_in[3];
    const float* bk = (const float*)d_in[4];
    const float* Wv = (const float*)d_in[5];
    const float* bv = (const float*)d_in[6];
    const float* Wo = (const float*)d_in[7];
    const float* bo = (const float*)d_in[8];
    float* out = (float*)d_out;

    size_t off = 0;
    auto alloc = [&](size_t bytes) {
        void* p = (char*)d_ws + off;
        off += (bytes + 255) & ~(size_t)255;
        return p;
    };
    _Float16* Xh    = (_Float16*)alloc((size_t)MM * HH * 2);
    _Float16* WqkvT = (_Float16*)alloc((size_t)3 * HH * HH * 2);
    _Float16* WoT   = (_Float16*)alloc((size_t)HH * HH * 2);
    _Float16* Qh    = (_Float16*)alloc((size_t)BB * NHH * SS * HDD * 2);
    _Float16* Kh    = (_Float16*)alloc((size_t)BB * NHH * SS * HDD * 2);
    _Float16* Vt    = (_Float16*)alloc((size_t)BB * NHH * SS * HDD * 2);
    _Float16* Ctx   = (_Float16*)alloc((size_t)MM * HH * 2);

    prep_kernel<<<dim3(16, 16, 5), 256, 0, stream>>>(
        hs, Wq, Wk, Wv, Wo, Xh, WqkvT, WoT);
    gemm_qkv_kernel<<<dim3(QKV_N / 256, MM / 256), 512, 0, stream>>>(
        Xh, WqkvT, bq, bk, bv, Qh, Kh, Vt);
    attn_kernel<<<dim3(16, NHH, BB), 512, 0, stream>>>(Qh, Kh, Vt, Ctx);
    gemm_out_kernel<<<dim3(HH / 128, MM / 128), 256, 0, stream>>>(
        Ctx, WoT, bo, out);
}

// Round 8
// 180.948 us; speedup vs baseline: 1.3873x; 1.0233x over previous
//
#include <hip/hip_runtime.h>
#include <hip/hip_bf16.h>

// Problem constants
#define BB 2
#define SS 2048
#define HH 1024
#define NHH 16
#define HDD 64
#define MM (BB*SS)        // 4096
#define QKV_N (3*HH)      // 3072

typedef _Float16 f16x8 __attribute__((ext_vector_type(8)));
typedef _Float16 f16x4 __attribute__((ext_vector_type(4)));
typedef float f32x4 __attribute__((ext_vector_type(4)));

#define MFMA16(a,b,c)  __builtin_amdgcn_mfma_f32_16x16x32_f16((a),(b),(c),0,0,0)
#define MFMA16K16(a,b,c) __builtin_amdgcn_mfma_f32_16x16x16f16((a),(b),(c),0,0,0)

// async global->LDS 16B per lane; LDS dest = wave-uniform base + lane*16
__device__ __forceinline__ void gl2lds16(const _Float16* g, _Float16* l) {
    __builtin_amdgcn_global_load_lds(
        (const __attribute__((address_space(1))) void*)g,
        (__attribute__((address_space(3))) void*)l, 16, 0, 0);
}

// single-instruction exp2 WITH compiler hazard handling (raw asm broke TRANS-op waits)
__device__ __forceinline__ float fexp2(float x) { return __builtin_amdgcn_exp2f(x); }

// ---------------- prep: z<4 transpose-cast W -> Wt fp16; z==4 cast X -> fp16 ------------
// grid (16,16,5), block 256.
__global__ __launch_bounds__(256) void prep_kernel(
    const float* __restrict__ X,
    const float* __restrict__ W0, const float* __restrict__ W1,
    const float* __restrict__ W2, const float* __restrict__ W3,
    _Float16* __restrict__ Xh,
    _Float16* __restrict__ WqkvT, _Float16* __restrict__ WoT)
{
    __shared__ float t[64][65];
    int z = blockIdx.z;
    int tid = threadIdx.x;
    if (z == 4) {
        int base = (blockIdx.y * 16 + blockIdx.x) * 256 + tid;
        const float4* xin = (const float4*)X;
        f16x4* xout = (f16x4*)Xh;
#pragma unroll
        for (int i = 0; i < 16; ++i) {
            float4 v = xin[base + i * 65536];
            f16x4 hh = {(_Float16)v.x, (_Float16)v.y, (_Float16)v.z, (_Float16)v.w};
            xout[base + i * 65536] = hh;
        }
        return;
    }
    const float* src = (z == 0) ? W0 : (z == 1) ? W1 : (z == 2) ? W2 : W3;
    _Float16* dst = (z < 3) ? (WqkvT + (size_t)z * HH * HH) : WoT;
    int k0 = blockIdx.y * 64, n0 = blockIdx.x * 64;
#pragma unroll
    for (int p = 0; p < 4; ++p) {
        int row = p * 16 + (tid >> 4);
        int col4 = (tid & 15) * 4;
        float4 v = *(const float4*)&src[(size_t)(k0 + row) * HH + n0 + col4];
        t[row][col4 + 0] = v.x; t[row][col4 + 1] = v.y;
        t[row][col4 + 2] = v.z; t[row][col4 + 3] = v.w;
    }
    __syncthreads();
#pragma unroll
    for (int p = 0; p < 2; ++p) {
        int nc = p * 32 + (tid >> 3);
        int ch = tid & 7;
        f16x8 o;
#pragma unroll
        for (int j = 0; j < 8; ++j) o[j] = (_Float16)t[ch * 8 + j][nc];
        *(f16x8*)&dst[(size_t)(n0 + nc) * HH + k0 + ch * 8] = o;
    }
}

// ---------------- QKV GEMM: 256x192 tile, 4-phase counted-vmcnt, 256 blocks = 1/CU ------
// R7's 256^2 4-phase measured +20% per-CU (2.78 vs 2.32 TF/CU) but lost to grid
// quantization (192 blocks / 256 CUs = 75%). BN=192 -> grid 16x16 = 256 = exact CU
// coverage. Wave tile 128x48 (acc[8][3]); bf[3][2] loaded once per K-step, held across
// phases; 12 MFMA/phase. Staging per K-step per wave: A 4 loads; B 192 rows -> waves
// 0-3 take 8 total, waves 4-7 take 6; vmcnt(2) at phase 1 drains each wave's OWN
// previous-step loads (8+2->2 and 6+2->2 both correct), keeping the 2 newest in flight.
// Epilogue: 192-wide tiles span Q/K/V boundaries (8-col groups are always pure since
// 8|1024): Q/K cols bounce via row-major region, V cols via transposed region; unified
// 6x512-slot store loop routes per group.
__global__ __launch_bounds__(512, 2) void gemm_qkv_kernel(
    const _Float16* __restrict__ A, const _Float16* __restrict__ Bt,
    const float* __restrict__ bias0, const float* __restrict__ bias1, const float* __restrict__ bias2,
    _Float16* __restrict__ Qh, _Float16* __restrict__ Kh, _Float16* __restrict__ Vt)
{
    __shared__ _Float16 smem[57344];      // 114688 B: A 2x16384 | B 2x12288 (U epilogue)

    // bijective XCD swizzle: 256 blocks = 32/XCD exactly
    int bid = blockIdx.y * 16 + blockIdx.x;
    int swzb = (bid & 7) * 32 + (bid >> 3);
    int bx = swzb & 15, by = swzb >> 4;
    int row0 = by * 256, n0 = bx * 192;

    int tid = threadIdx.x;
    int w = tid >> 6, l = tid & 63, m16 = l & 15, quad = l >> 4;
    int wm = w >> 2, wn = w & 3;          // wave tile: rows wm*128, cols wn*48

    // staging: each instr covers 16 rows x 32 f16; lane-only XOR swizzle (proven algebra)
    int srow = w * 16 + (l >> 2);
    int sch = (l & 3) ^ ((l >> 2) & 3) ^ ((l >> 4) & 3);
    const _Float16* aptr = A + (size_t)(row0 + srow) * HH + sch * 8;
    const _Float16* bptr = Bt + (size_t)(n0 + srow) * HH + sch * 8;

    int gsw = (m16 & 3) ^ ((m16 >> 2) & 3);
    int acol = (quad ^ gsw) * 8;

    f32x4 zero4 = {0.f, 0.f, 0.f, 0.f};
    f32x4 acc[8][3];
#pragma unroll
    for (int i = 0; i < 8; ++i)
#pragma unroll
        for (int j = 0; j < 3; ++j) acc[i][j] = zero4;

    // LDS f16 offsets: A[buf][ks][256][32] @ buf*16384 + ks*8192;
    //                  B[buf][ks][192][32] @ 32768 + buf*12288 + ks*6144.
    auto stageA = [&](int s, int h, int ks) {
        gl2lds16(aptr + (size_t)h * 128 * HH + s * 64 + ks * 32,
                 smem + (s & 1) * 16384 + ks * 8192 + (h * 128 + w * 16) * 32);
    };
    auto stageB = [&](int s, int h, int ks) {   // h==1 only issued by waves 0-3
        gl2lds16(bptr + (size_t)h * 128 * HH + s * 64 + ks * 32,
                 smem + 32768 + (s & 1) * 12288 + ks * 6144 + (h * 128 + w * 16) * 32);
    };

    // prologue: all of K-step 0 (waves 0-3: 8 loads, waves 4-7: 6)
    stageA(0, 0, 0); stageA(0, 0, 1); stageA(0, 1, 0); stageA(0, 1, 1);
    stageB(0, 0, 0); stageB(0, 0, 1);
    if (w < 4) { stageB(0, 1, 0); stageB(0, 1, 1); }

    for (int s = 0; s < 16; ++s) {
        const _Float16* Ab = smem + (s & 1) * 16384;
        const _Float16* Bb = smem + 32768 + (s & 1) * 12288;
        bool pf = (s + 1 < 16);
        f16x8 af[2][2], bf[3][2];

        // ---- phase 1: stage A(s+1,h0); counted vmcnt; B-frags + A fi{0,1} ----
        if (pf) { stageA(s + 1, 0, 0); stageA(s + 1, 0, 1);
                  asm volatile("s_waitcnt vmcnt(2)" ::: "memory"); }
        else    { asm volatile("s_waitcnt vmcnt(0)" ::: "memory"); }
        asm volatile("s_barrier" ::: "memory");
#pragma unroll
        for (int fj = 0; fj < 3; ++fj)
#pragma unroll
            for (int ks = 0; ks < 2; ++ks)
                bf[fj][ks] = *(const f16x8*)&Bb[ks * 6144 + (wn * 48 + fj * 16 + m16) * 32 + acol];
#pragma unroll
        for (int i = 0; i < 2; ++i)
#pragma unroll
            for (int ks = 0; ks < 2; ++ks)
                af[i][ks] = *(const f16x8*)&Ab[ks * 8192 + (wm * 128 + i * 16 + m16) * 32 + acol];
        __builtin_amdgcn_s_setprio(1);
#pragma unroll
        for (int i = 0; i < 2; ++i)
#pragma unroll
            for (int fj = 0; fj < 3; ++fj) {
                acc[i][fj] = MFMA16(af[i][0], bf[fj][0], acc[i][fj]);
                acc[i][fj] = MFMA16(af[i][1], bf[fj][1], acc[i][fj]);
            }
        __builtin_amdgcn_s_setprio(0);
        asm volatile("s_barrier" ::: "memory");

        // ---- phases 2..4: A fi{2p,2p+1}; one stage-pair each ----
#pragma unroll
        for (int p = 1; p < 4; ++p) {
            if (pf) {
                if (p == 1)      { stageA(s + 1, 1, 0); stageA(s + 1, 1, 1); }
                else if (p == 2) { stageB(s + 1, 0, 0); stageB(s + 1, 0, 1); }
                else if (w < 4)  { stageB(s + 1, 1, 0); stageB(s + 1, 1, 1); }
            }
#pragma unroll
            for (int i = 0; i < 2; ++i)
#pragma unroll
                for (int ks = 0; ks < 2; ++ks)
                    af[i][ks] = *(const f16x8*)&Ab[ks * 8192 + (wm * 128 + (2 * p + i) * 16 + m16) * 32 + acol];
            __builtin_amdgcn_s_setprio(1);
#pragma unroll
            for (int i = 0; i < 2; ++i)
#pragma unroll
                for (int fj = 0; fj < 3; ++fj) {
                    acc[2 * p + i][fj] = MFMA16(af[i][0], bf[fj][0], acc[2 * p + i][fj]);
                    acc[2 * p + i][fj] = MFMA16(af[i][1], bf[fj][1], acc[2 * p + i][fj]);
                }
            __builtin_amdgcn_s_setprio(0);
            asm volatile("s_barrier" ::: "memory");   // phase-4's = buffer-reuse fence
        }
    }

    // ---- epilogue: per-8-col-group routed, two 128-row halves ----
    // QK region: [128][200] @ f16 0 (row-major). V region: [192][136] @ f16 25600 (transposed).
    int b = row0 >> 11, s0 = row0 & 2047;

#pragma unroll
    for (int rh = 0; rh < 2; ++rh) {
        __syncthreads();
        if (wm == rh) {
#pragma unroll
            for (int fj = 0; fj < 3; ++fj) {
                int n_local = wn * 48 + fj * 16 + m16;
                int n = n0 + n_local;
                int which = n >> 10;
                const float* bp = (which == 0) ? bias0 : (which == 1) ? bias1 : bias2;
                float bi = bp[n & 1023];
#pragma unroll
                for (int i = 0; i < 8; ++i)
#pragma unroll
                    for (int r = 0; r < 4; ++r) {
                        int m_loc = i * 16 + quad * 4 + r;          // 0..127 within half
                        float v = acc[i][fj][r] + bi;
                        if (which == 0) v *= 0.18033688011112042f;  // (1/sqrt(64))*log2(e)
                        if (which == 2) smem[25600 + n_local * 136 + m_loc] = (_Float16)v;
                        else            smem[m_loc * 200 + n_local] = (_Float16)v;
                    }
            }
        }
        __syncthreads();
        int hs0 = s0 + rh * 128;
        // unified store loop: 3072 slots = 128 rows x 24 groups (div by literal 24)
#pragma unroll
        for (int p = 0; p < 6; ++p) {
            int idx = p * 512 + tid;
            int m_local = idx / 24;
            int cg = idx - m_local * 24;
            int nc = n0 + cg * 8;                  // group base (group is which-pure)
            int which = nc >> 10;
            if (which == 2) {
                int nl = cg * 8 + (m_local & 7);   // V column within tile
                int schunk = m_local >> 3;         // 0..15
                f16x8 v = *(const f16x8*)&smem[25600 + nl * 136 + schunk * 8];
                int nn = n0 + nl;
                int hh = (nn & 1023) >> 6, d = nn & 63;
                *(f16x8*)&Vt[((size_t)(b * NHH + hh) * HDD + d) * SS + hs0 + schunk * 8] = v;
            } else {
                f16x8 v = *(const f16x8*)&smem[m_local * 200 + cg * 8];
                int hh = (nc & 1023) >> 6, d = nc & 63;
                _Float16* dst = which ? Kh : Qh;
                *(f16x8*)&dst[((size_t)(b * NHH + hh) * SS + hs0 + m_local) * HDD + d] = v;
            }
        }
    }
}

// ---------------- Output projection: 128x128 tile, 3-stage, direct fp32 store -----------
// (proven R1 version)
__global__ __launch_bounds__(256) void gemm_out_kernel(
    const _Float16* __restrict__ A, const _Float16* __restrict__ Bt,
    const float* __restrict__ bias0, float* __restrict__ Out)
{
    const int K = HH;
    const int NT = K / 32;
    __shared__ _Float16 smem[24576];          // 49152 B: 3-stage bufs

    int row0 = blockIdx.y * 128, n0 = blockIdx.x * 128;
    int tid = threadIdx.x;
    int w = tid >> 6, l = tid & 63, m16 = l & 15, quad = l >> 4;
    int wm = w >> 1, wn = w & 1;

    int srow = w * 32 + (l >> 2);
    int sch = (l & 3) ^ ((l >> 2) & 3) ^ ((l >> 4) & 3);
    const _Float16* aptr = A + (size_t)(row0 + srow) * K + sch * 8;
    const _Float16* bptr = Bt + (size_t)(n0 + srow) * K + sch * 8;

    int gsw = (m16 & 3) ^ ((m16 >> 2) & 3);
    int acol = (quad ^ gsw) * 8;

    f32x4 zero4 = {0.f, 0.f, 0.f, 0.f};
    f32x4 acc[4][4];
#pragma unroll
    for (int i = 0; i < 4; ++i)
#pragma unroll
        for (int j = 0; j < 4; ++j) acc[i][j] = zero4;

    auto stage = [&](int t, int s) {
        int k0 = t * 32;
        int ao = s * 4096 + (w * 32) * 32;
        int bo = 12288 + s * 4096 + (w * 32) * 32;
        gl2lds16(aptr + k0, smem + ao);
        gl2lds16(aptr + (size_t)16 * K + k0, smem + ao + 16 * 32);
        gl2lds16(bptr + k0, smem + bo);
        gl2lds16(bptr + (size_t)16 * K + k0, smem + bo + 16 * 32);
    };

    stage(0, 0);
    stage(1, 1);
    int cur = 0;
    for (int t = 0; t < NT; ++t) {
        if (t < NT - 1) asm volatile("s_waitcnt vmcnt(4)" ::: "memory");
        else            asm volatile("s_waitcnt vmcnt(0)" ::: "memory");
        asm volatile("s_barrier" ::: "memory");
        if (t + 2 < NT) {
            int nxt = cur + 2; if (nxt >= 3) nxt -= 3;
            stage(t + 2, nxt);
        }
        const _Float16* Asr = smem + cur * 4096;
        const _Float16* Bsr = smem + 12288 + cur * 4096;
        f16x8 af[4], bf[4];
#pragma unroll
        for (int i = 0; i < 4; ++i)
            af[i] = *(const f16x8*)&Asr[(wm * 64 + i * 16 + m16) * 32 + acol];
#pragma unroll
        for (int j = 0; j < 4; ++j)
            bf[j] = *(const f16x8*)&Bsr[(wn * 64 + j * 16 + m16) * 32 + acol];
#pragma unroll
        for (int i = 0; i < 4; ++i)
#pragma unroll
            for (int j = 0; j < 4; ++j)
                acc[i][j] = MFMA16(af[i], bf[j], acc[i][j]);
        cur = (cur == 2) ? 0 : cur + 1;
    }

#pragma unroll
    for (int j = 0; j < 4; ++j) {
        int n = n0 + wn * 64 + j * 16 + m16;
        float bi = bias0[n];
#pragma unroll
        for (int i = 0; i < 4; ++i)
#pragma unroll
            for (int r = 0; r < 4; ++r) {
                int mg = row0 + wm * 64 + i * 16 + quad * 4 + r;
                Out[(size_t)mg * HH + n] = acc[i][j][r] + bi;
            }
    }
}

// ---------------- Flash attention: S^T formulation, 8-wave tile-split (proven ~32us) ----
__global__ __launch_bounds__(512, 4) void attn_kernel(
    const _Float16* __restrict__ Qh, const _Float16* __restrict__ Kh,
    const _Float16* __restrict__ Vt, _Float16* __restrict__ Ctx)
{
    __shared__ _Float16 KV[3 * 8192];     // 49152 B, 3-stage K+V

    int tid = threadIdx.x;
    int w = tid >> 6, l = tid & 63;
    int m16 = l & 15, quad = l >> 4;
    int b = blockIdx.z, h = blockIdx.y;
    int tA = blockIdx.x, tB = 31 - tA;
    int half = w >> 2, wq = w & 3;
    int myT = half ? tB : tA;             // this wave's q-tile index

    const _Float16* Q = Qh + (size_t)(b * NHH + h) * SS * HDD;
    const _Float16* K = Kh + (size_t)(b * NHH + h) * SS * HDD;
    const _Float16* V = Vt + (size_t)(b * NHH + h) * HDD * SS;

    int q = myT * 64 + wq * 16 + m16;     // this lane's q row (S^T: q = lane&15)
    f16x8 aq0 = *(const f16x8*)(Q + (size_t)q * HDD + quad * 8);
    f16x8 aq1 = *(const f16x8*)(Q + (size_t)q * HDD + 32 + quad * 8);

    // staging: wave w covers rows [w*8, w*8+8), one 8-row instr per matrix
    int srow = w * 8 + (l >> 3);
    int sch = (l & 7) ^ (l >> 3);
    const _Float16* kg = K + (size_t)srow * HDD + sch * 8;
    const _Float16* vg = V + (size_t)srow * SS + sch * 8;

    auto stage = [&](int t, int s) {
        int kt = t * 64;
        _Float16* kb = &KV[s * 8192];
        _Float16* vb = &KV[s * 8192 + 4096];
        gl2lds16(kg + (size_t)kt * HDD, kb + (w * 8) * 64);
        gl2lds16(vg + kt, vb + (w * 8) * 64);
    };

    int swz = m16 & 7;
    int cka = (quad ^ swz) * 8;          // K-frag d-chunk 0..31
    int ckb = ((quad + 4) ^ swz) * 8;    // K-frag d-chunk 32..63
    int vco[4];
#pragma unroll
    for (int s = 0; s < 4; ++s)
        vco[s] = (((s * 2 + (quad >> 1)) ^ swz) * 8) + (quad & 1) * 4;

    f32x4 zero4 = {0.f, 0.f, 0.f, 0.f};
    const f16x4 ones4 = {(_Float16)1.f, (_Float16)1.f, (_Float16)1.f, (_Float16)1.f};
    f32x4 o[4];                          // O^T: row d=c*16+quad*4+r, col q=m16
#pragma unroll
    for (int c = 0; c < 4; ++c) o[c] = zero4;
    f32x4 lacc = zero4;                  // softmax denominator (all rows identical)

    stage(0, 0);
    stage(1, 1);
    int cur = 0;
    for (int t = 0; t <= tB; ++t) {
        int kt = t * 64;
        if (t < tB) asm volatile("s_waitcnt vmcnt(2)" ::: "memory");
        else        asm volatile("s_waitcnt vmcnt(0)" ::: "memory");
        asm volatile("s_barrier" ::: "memory");
        if (t + 2 <= tB) {
            int nxt = cur + 2; if (nxt >= 3) nxt -= 3;
            stage(t + 2, nxt);
        }

        if (t <= myT) {                   // wave-uniform: body only while tile active
            const _Float16* kb = &KV[cur * 8192];
            const _Float16* vb = &KV[cur * 8192 + 4096];
            f16x8 bk[4][2];
#pragma unroll
            for (int s = 0; s < 4; ++s) {
                const _Float16* kr = kb + (s * 16 + m16) * 64;
                bk[s][0] = *(const f16x8*)(kr + cka);
                bk[s][1] = *(const f16x8*)(kr + ckb);
            }
            f16x4 av[4][4];              // [c d-block][s key-chunk]
#pragma unroll
            for (int c = 0; c < 4; ++c) {
                const _Float16* vr = vb + (c * 16 + m16) * 64;
#pragma unroll
                for (int s = 0; s < 4; ++s)
                    av[c][s] = *(const f16x4*)(vr + vco[s]);
            }

            f32x4 st[4];
#pragma unroll
            for (int s = 0; s < 4; ++s) {
                st[s] = MFMA16(bk[s][0], aq0, zero4);
                st[s] = MFMA16(bk[s][1], aq1, st[s]);
            }
            f16x4 pt[4];
            if (t == myT) {              // masked (diagonal) tile
#pragma unroll
                for (int s = 0; s < 4; ++s)
#pragma unroll
                    for (int r = 0; r < 4; ++r) {
                        float p = fexp2(st[s][r]);
                        int key = kt + s * 16 + quad * 4 + r;
                        if (key > q) p = 0.f;
                        pt[s][r] = (_Float16)p;
                    }
            } else {
#pragma unroll
                for (int s = 0; s < 4; ++s)
#pragma unroll
                    for (int r = 0; r < 4; ++r)
                        pt[s][r] = (_Float16)fexp2(st[s][r]);
            }
#pragma unroll
            for (int s = 0; s < 4; ++s)
                lacc = MFMA16K16(ones4, pt[s], lacc);
#pragma unroll
            for (int c = 0; c < 4; ++c)
#pragma unroll
                for (int s = 0; s < 4; ++s)
                    o[c] = MFMA16K16(av[c][s], pt[s], o[c]);
        }

        cur = (cur == 2) ? 0 : cur + 1;
    }

    // epilogue: normalize (denominator identical across rows/quads for a given q), store O^T
    float inv = 1.0f / lacc[0];
    size_t rowoff = ((size_t)(b * SS) + q) * HH + h * HDD;
#pragma unroll
    for (int c = 0; c < 4; ++c) {
        f16x4 ov;
#pragma unroll
        for (int r = 0; r < 4; ++r) ov[r] = (_Float16)(o[c][r] * inv);
        *(f16x4*)&Ctx[rowoff + c * 16 + quad * 4] = ov;
    }
}

extern "C" void kernel_launch(void* const* d_in, const int* in_sizes, int n_in,
                              void* d_out, int out_size, void* d_ws, size_t ws_size,
                              hipStream_t stream) {
    const float* hs = (const float*)d_in[0];
    const float* Wq = (const float*)d_in[1];
    const float* bq = (const float*)d_in[2];
    const float* Wk = (const float*)d_in[3];
    const float* bk = (const float*)d_in[4];
    const float* Wv = (const float*)d_in[5];
    const float* bv = (const float*)d_in[6];
    const float* Wo = (const float*)d_in[7];
    const float* bo = (const float*)d_in[8];
    float* out = (float*)d_out;

    size_t off = 0;
    auto alloc = [&](size_t bytes) {
        void* p = (char*)d_ws + off;
        off += (bytes + 255) & ~(size_t)255;
        return p;
    };
    _Float16* Xh    = (_Float16*)alloc((size_t)MM * HH * 2);
    _Float16* WqkvT = (_Float16*)alloc((size_t)3 * HH * HH * 2);
    _Float16* WoT   = (_Float16*)alloc((size_t)HH * HH * 2);
    _Float16* Qh    = (_Float16*)alloc((size_t)BB * NHH * SS * HDD * 2);
    _Float16* Kh    = (_Float16*)alloc((size_t)BB * NHH * SS * HDD * 2);
    _Float16* Vt    = (_Float16*)alloc((size_t)BB * NHH * SS * HDD * 2);
    _Float16* Ctx   = (_Float16*)alloc((size_t)MM * HH * 2);

    prep_kernel<<<dim3(16, 16, 5), 256, 0, stream>>>(
        hs, Wq, Wk, Wv, Wo, Xh, WqkvT, WoT);
    gemm_qkv_kernel<<<dim3(16, 16), 512, 0, stream>>>(
        Xh, WqkvT, bq, bk, bv, Qh, Kh, Vt);
    attn_kernel<<<dim3(16, NHH, BB), 512, 0, stream>>>(Qh, Kh, Vt, Ctx);
    gemm_out_kernel<<<dim3(HH / 128, MM / 128), 256, 0, stream>>>(
        Ctx, WoT, bo, out);
}

// Round 10
// 178.083 us; speedup vs baseline: 1.4096x; 1.0161x over previous
//
#include <hip/hip_runtime.h>
#include <hip/hip_bf16.h>

// Problem constants
#define BB 2
#define SS 2048
#define HH 1024
#define NHH 16
#define HDD 64
#define MM (BB*SS)        // 4096
#define QKV_N (3*HH)      // 3072

typedef _Float16 f16x8 __attribute__((ext_vector_type(8)));
typedef _Float16 f16x4 __attribute__((ext_vector_type(4)));
typedef float f32x4 __attribute__((ext_vector_type(4)));

#define MFMA16(a,b,c)  __builtin_amdgcn_mfma_f32_16x16x32_f16((a),(b),(c),0,0,0)
#define MFMA16K16(a,b,c) __builtin_amdgcn_mfma_f32_16x16x16f16((a),(b),(c),0,0,0)

// async global->LDS 16B per lane; LDS dest = wave-uniform base + lane*16
__device__ __forceinline__ void gl2lds16(const _Float16* g, _Float16* l) {
    __builtin_amdgcn_global_load_lds(
        (const __attribute__((address_space(1))) void*)g,
        (__attribute__((address_space(3))) void*)l, 16, 0, 0);
}

// single-instruction exp2 WITH compiler hazard handling (raw asm broke TRANS-op waits)
__device__ __forceinline__ float fexp2(float x) { return __builtin_amdgcn_exp2f(x); }

// ---------------- prep: z<4 transpose-cast W -> Wt fp16; z==4 cast X -> fp16 ------------
// grid (16,16,5), block 256.
__global__ __launch_bounds__(256) void prep_kernel(
    const float* __restrict__ X,
    const float* __restrict__ W0, const float* __restrict__ W1,
    const float* __restrict__ W2, const float* __restrict__ W3,
    _Float16* __restrict__ Xh,
    _Float16* __restrict__ WqkvT, _Float16* __restrict__ WoT)
{
    __shared__ float t[64][65];
    int z = blockIdx.z;
    int tid = threadIdx.x;
    if (z == 4) {
        int base = (blockIdx.y * 16 + blockIdx.x) * 256 + tid;
        const float4* xin = (const float4*)X;
        f16x4* xout = (f16x4*)Xh;
#pragma unroll
        for (int i = 0; i < 16; ++i) {
            float4 v = xin[base + i * 65536];
            f16x4 hh = {(_Float16)v.x, (_Float16)v.y, (_Float16)v.z, (_Float16)v.w};
            xout[base + i * 65536] = hh;
        }
        return;
    }
    const float* src = (z == 0) ? W0 : (z == 1) ? W1 : (z == 2) ? W2 : W3;
    _Float16* dst = (z < 3) ? (WqkvT + (size_t)z * HH * HH) : WoT;
    int k0 = blockIdx.y * 64, n0 = blockIdx.x * 64;
#pragma unroll
    for (int p = 0; p < 4; ++p) {
        int row = p * 16 + (tid >> 4);
        int col4 = (tid & 15) * 4;
        float4 v = *(const float4*)&src[(size_t)(k0 + row) * HH + n0 + col4];
        t[row][col4 + 0] = v.x; t[row][col4 + 1] = v.y;
        t[row][col4 + 2] = v.z; t[row][col4 + 3] = v.w;
    }
    __syncthreads();
#pragma unroll
    for (int p = 0; p < 2; ++p) {
        int nc = p * 32 + (tid >> 3);
        int ch = tid & 7;
        f16x8 o;
#pragma unroll
        for (int j = 0; j < 8; ++j) o[j] = (_Float16)t[ch * 8 + j][nc];
        *(f16x8*)&dst[(size_t)(n0 + nc) * HH + k0 + ch * 8] = o;
    }
}

// ---------------- QKV GEMM: 128x128 tile, 3-stage pipeline (proven 43.5us, FINAL) -------
// Three structures measured: this (43.5), 256^2 4-phase @192 blocks (48.4, grid-quantized),
// 256x192 4-phase @256 blocks (44.7, phase-diluted). The phase schedule's per-CU gain is
// always cancelled on this K=1024 shape — this is the practical floor.
__global__ __launch_bounds__(256) void gemm_qkv_kernel(
    const _Float16* __restrict__ A, const _Float16* __restrict__ Bt,
    const float* __restrict__ bias0, const float* __restrict__ bias1, const float* __restrict__ bias2,
    _Float16* __restrict__ Qh, _Float16* __restrict__ Kh, _Float16* __restrict__ Vt)
{
    const int K = HH;
    const int NT = K / 32;
    __shared__ _Float16 smem[24576];          // 49152 B: 3-stage bufs U epilogue tile 128x132

    int row0 = blockIdx.y * 128, n0 = blockIdx.x * 128;
    int tid = threadIdx.x;
    int w = tid >> 6, l = tid & 63, m16 = l & 15, quad = l >> 4;
    int wm = w >> 1, wn = w & 1;

    int srow = w * 32 + (l >> 2);
    int sch = (l & 3) ^ ((l >> 2) & 3) ^ ((l >> 4) & 3);
    const _Float16* aptr = A + (size_t)(row0 + srow) * K + sch * 8;
    const _Float16* bptr = Bt + (size_t)(n0 + srow) * K + sch * 8;

    int gsw = (m16 & 3) ^ ((m16 >> 2) & 3);
    int acol = (quad ^ gsw) * 8;

    f32x4 zero4 = {0.f, 0.f, 0.f, 0.f};
    f32x4 acc[4][4];
#pragma unroll
    for (int i = 0; i < 4; ++i)
#pragma unroll
        for (int j = 0; j < 4; ++j) acc[i][j] = zero4;

    auto stage = [&](int t, int s) {
        int k0 = t * 32;
        int ao = s * 4096 + (w * 32) * 32;
        int bo = 12288 + s * 4096 + (w * 32) * 32;
        gl2lds16(aptr + k0, smem + ao);
        gl2lds16(aptr + (size_t)16 * K + k0, smem + ao + 16 * 32);
        gl2lds16(bptr + k0, smem + bo);
        gl2lds16(bptr + (size_t)16 * K + k0, smem + bo + 16 * 32);
    };

    stage(0, 0);
    stage(1, 1);
    int cur = 0;
    for (int t = 0; t < NT; ++t) {
        if (t < NT - 1) asm volatile("s_waitcnt vmcnt(4)" ::: "memory");
        else            asm volatile("s_waitcnt vmcnt(0)" ::: "memory");
        asm volatile("s_barrier" ::: "memory");
        if (t + 2 < NT) {
            int nxt = cur + 2; if (nxt >= 3) nxt -= 3;
            stage(t + 2, nxt);
        }
        const _Float16* Asr = smem + cur * 4096;
        const _Float16* Bsr = smem + 12288 + cur * 4096;
        f16x8 af[4], bf[4];
#pragma unroll
        for (int i = 0; i < 4; ++i)
            af[i] = *(const f16x8*)&Asr[(wm * 64 + i * 16 + m16) * 32 + acol];
#pragma unroll
        for (int j = 0; j < 4; ++j)
            bf[j] = *(const f16x8*)&Bsr[(wn * 64 + j * 16 + m16) * 32 + acol];
#pragma unroll
        for (int i = 0; i < 4; ++i)
#pragma unroll
            for (int j = 0; j < 4; ++j)
                acc[i][j] = MFMA16(af[i], bf[j], acc[i][j]);
        cur = (cur == 2) ? 0 : cur + 1;
    }

    // ---- epilogue: bias (+scale for Q), LDS bounce, coalesced stores ----
    int which = n0 >> 10;                     // 0=Q 1=K 2=V (block is pure)
    const float* bias = (which == 0) ? bias0 : (which == 1) ? bias1 : bias2;
    __syncthreads();
#pragma unroll
    for (int j = 0; j < 4; ++j) {
        int n_local = wn * 64 + j * 16 + m16;
        float bi = bias[(n0 + n_local) & 1023];
#pragma unroll
        for (int i = 0; i < 4; ++i)
#pragma unroll
            for (int r = 0; r < 4; ++r) {
                int m_local = wm * 64 + i * 16 + quad * 4 + r;
                float v = acc[i][j][r] + bi;
                if (which == 0) v *= 0.18033688011112042f;  // (1/sqrt(64))*log2(e)
                if (which == 2) smem[n_local * 132 + m_local] = (_Float16)v;   // transposed
                else            smem[m_local * 132 + n_local] = (_Float16)v;
            }
    }
    __syncthreads();

    int b = row0 >> 11, s0 = row0 & 2047;
    if (which == 2) {
#pragma unroll
        for (int p = 0; p < 8; ++p) {
            int n_local = p * 16 + (tid >> 4);
            int schunk = tid & 15;
            f16x8 v = *(const f16x8*)&smem[n_local * 132 + schunk * 8];
            int nw = (n0 + n_local) & 1023;
            int hh = nw >> 6, d = nw & 63;
            *(f16x8*)&Vt[((size_t)(b * NHH + hh) * HDD + d) * SS + s0 + schunk * 8] = v;
        }
    } else {
        _Float16* dst = (which == 0) ? Qh : Kh;
        int hh0 = (n0 & 1023) >> 6;
#pragma unroll
        for (int p = 0; p < 8; ++p) {
            int m_local = p * 16 + (tid >> 4);
            int seg = tid & 15;
            f16x8 v = *(const f16x8*)&smem[m_local * 132 + seg * 8];
            int hh = hh0 + (seg >> 3), d = (seg & 7) * 8;
            *(f16x8*)&dst[((size_t)(b * NHH + hh) * SS + s0 + m_local) * HDD + d] = v;
        }
    }
}

// ---------------- Output projection: 128x128 tile, split-K WITHIN block -----------------
// Old: 256 blocks = 1 block/CU, 4 waves = 1 wave/SIMD — most latency-exposed kernel.
// Prior fixes failed: smaller tile (halved MFMA/phase), cross-block split-K (atomics).
// This: 512 threads, waves 0-3 compute K[0:512], waves 4-7 K[512:1024]; each group runs
// the byte-identical proven 3-stage pipeline on its own 48KB LDS region (96KB total;
// grid 256 = 1 block/CU is binding anyway). Serial K-chain per block halves (32->16
// tiles) at unchanged MFMA/phase; 2 waves/SIMD give two independent chains to
// interleave. Epilogue: group 1 deposits acc via stride-65-f32 LDS (65 = 1 mod 32 ->
// conflict-free), group 0 adds + bias + stores (f32 add reorder exact within tolerance).
__global__ __launch_bounds__(512, 2) void gemm_out_kernel(
    const _Float16* __restrict__ A, const _Float16* __restrict__ Bt,
    const float* __restrict__ bias0, float* __restrict__ Out)
{
    const int K = HH;
    const int NT = 16;                        // 16 x 32 = 512 of K per group
    __shared__ _Float16 smem[49152];          // 98304 B: group g 3-stage bufs at g*24576

    int row0 = blockIdx.y * 128, n0 = blockIdx.x * 128;
    int tid = threadIdx.x;
    int w = tid >> 6, l = tid & 63, m16 = l & 15, quad = l >> 4;
    int kg = w >> 2, wl = w & 3;              // K-group, wave-in-group
    int wm = wl >> 1, wn = wl & 1;
    int kbase = kg * 512;
    _Float16* gsm = smem + kg * 24576;

    int srow = wl * 32 + (l >> 2);
    int sch = (l & 3) ^ ((l >> 2) & 3) ^ ((l >> 4) & 3);
    const _Float16* aptr = A + (size_t)(row0 + srow) * K + kbase + sch * 8;
    const _Float16* bptr = Bt + (size_t)(n0 + srow) * K + kbase + sch * 8;

    int gsw = (m16 & 3) ^ ((m16 >> 2) & 3);
    int acol = (quad ^ gsw) * 8;

    f32x4 zero4 = {0.f, 0.f, 0.f, 0.f};
    f32x4 acc[4][4];
#pragma unroll
    for (int i = 0; i < 4; ++i)
#pragma unroll
        for (int j = 0; j < 4; ++j) acc[i][j] = zero4;

    auto stage = [&](int t, int s) {
        int k0 = t * 32;
        int ao = s * 4096 + (wl * 32) * 32;
        int bo = 12288 + s * 4096 + (wl * 32) * 32;
        gl2lds16(aptr + k0, gsm + ao);
        gl2lds16(aptr + (size_t)16 * K + k0, gsm + ao + 16 * 32);
        gl2lds16(bptr + k0, gsm + bo);
        gl2lds16(bptr + (size_t)16 * K + k0, gsm + bo + 16 * 32);
    };

    stage(0, 0);
    stage(1, 1);
    int cur = 0;
    for (int t = 0; t < NT; ++t) {
        // per-wave vmcnt counts its OWN loads; barriers block-wide, both groups lockstep
        if (t < NT - 1) asm volatile("s_waitcnt vmcnt(4)" ::: "memory");
        else            asm volatile("s_waitcnt vmcnt(0)" ::: "memory");
        asm volatile("s_barrier" ::: "memory");
        if (t + 2 < NT) {
            int nxt = cur + 2; if (nxt >= 3) nxt -= 3;
            stage(t + 2, nxt);
        }
        const _Float16* Asr = gsm + cur * 4096;
        const _Float16* Bsr = gsm + 12288 + cur * 4096;
        f16x8 af[4], bf[4];
#pragma unroll
        for (int i = 0; i < 4; ++i)
            af[i] = *(const f16x8*)&Asr[(wm * 64 + i * 16 + m16) * 32 + acol];
#pragma unroll
        for (int j = 0; j < 4; ++j)
            bf[j] = *(const f16x8*)&Bsr[(wn * 64 + j * 16 + m16) * 32 + acol];
#pragma unroll
        for (int i = 0; i < 4; ++i)
#pragma unroll
            for (int j = 0; j < 4; ++j)
                acc[i][j] = MFMA16(af[i], bf[j], acc[i][j]);
        cur = (cur == 2) ? 0 : cur + 1;
    }

    // ---- cross-group reduce: stride-65 f32 slots (conflict-free scalar access) ----
    float* red = (float*)smem;                // 256 lanes x 65 f32 = 66560 B < 98304
    __syncthreads();                          // all waves done with staging-buffer reads
    if (kg == 1) {
        float* slot = red + (size_t)(wl * 64 + l) * 65;
#pragma unroll
        for (int i = 0; i < 4; ++i)
#pragma unroll
            for (int j = 0; j < 4; ++j)
#pragma unroll
                for (int r = 0; r < 4; ++r)
                    slot[i * 16 + j * 4 + r] = acc[i][j][r];
    }
    __syncthreads();
    if (kg == 0) {
        const float* slot = red + (size_t)(wl * 64 + l) * 65;
#pragma unroll
        for (int j = 0; j < 4; ++j) {
            int n = n0 + wn * 64 + j * 16 + m16;
            float bi = bias0[n];
#pragma unroll
            for (int i = 0; i < 4; ++i)
#pragma unroll
                for (int r = 0; r < 4; ++r) {
                    int mg = row0 + wm * 64 + i * 16 + quad * 4 + r;
                    Out[(size_t)mg * HH + n] = acc[i][j][r] + slot[i * 16 + j * 4 + r] + bi;
                }
        }
    }
}

// ---------------- Flash attention: S^T formulation, 8-wave tile-split (proven ~32us) ----
// grid (16, NH, B), block 512 (8 waves). Waves 0-3 own q-tile tA=bx, waves 4-7 own
// tB=31-tA. Pairing balances block durations; unpaired (grid starvation) and KV-parity
// (register spill) variants both regressed.
__global__ __launch_bounds__(512, 4) void attn_kernel(
    const _Float16* __restrict__ Qh, const _Float16* __restrict__ Kh,
    const _Float16* __restrict__ Vt, _Float16* __restrict__ Ctx)
{
    __shared__ _Float16 KV[3 * 8192];     // 49152 B, 3-stage K+V

    int tid = threadIdx.x;
    int w = tid >> 6, l = tid & 63;
    int m16 = l & 15, quad = l >> 4;
    int b = blockIdx.z, h = blockIdx.y;
    int tA = blockIdx.x, tB = 31 - tA;
    int half = w >> 2, wq = w & 3;
    int myT = half ? tB : tA;             // this wave's q-tile index

    const _Float16* Q = Qh + (size_t)(b * NHH + h) * SS * HDD;
    const _Float16* K = Kh + (size_t)(b * NHH + h) * SS * HDD;
    const _Float16* V = Vt + (size_t)(b * NHH + h) * HDD * SS;

    int q = myT * 64 + wq * 16 + m16;     // this lane's q row (S^T: q = lane&15)
    f16x8 aq0 = *(const f16x8*)(Q + (size_t)q * HDD + quad * 8);
    f16x8 aq1 = *(const f16x8*)(Q + (size_t)q * HDD + 32 + quad * 8);

    // staging: wave w covers rows [w*8, w*8+8), one 8-row instr per matrix
    int srow = w * 8 + (l >> 3);
    int sch = (l & 7) ^ (l >> 3);
    const _Float16* kg = K + (size_t)srow * HDD + sch * 8;
    const _Float16* vg = V + (size_t)srow * SS + sch * 8;

    auto stage = [&](int t, int s) {
        int kt = t * 64;
        _Float16* kb = &KV[s * 8192];
        _Float16* vb = &KV[s * 8192 + 4096];
        gl2lds16(kg + (size_t)kt * HDD, kb + (w * 8) * 64);
        gl2lds16(vg + kt, vb + (w * 8) * 64);
    };

    int swz = m16 & 7;
    int cka = (quad ^ swz) * 8;          // K-frag d-chunk 0..31
    int ckb = ((quad + 4) ^ swz) * 8;    // K-frag d-chunk 32..63
    int vco[4];
#pragma unroll
    for (int s = 0; s < 4; ++s)
        vco[s] = (((s * 2 + (quad >> 1)) ^ swz) * 8) + (quad & 1) * 4;

    f32x4 zero4 = {0.f, 0.f, 0.f, 0.f};
    const f16x4 ones4 = {(_Float16)1.f, (_Float16)1.f, (_Float16)1.f, (_Float16)1.f};
    f32x4 o[4];                          // O^T: row d=c*16+quad*4+r, col q=m16
#pragma unroll
    for (int c = 0; c < 4; ++c) o[c] = zero4;
    f32x4 lacc = zero4;                  // softmax denominator (all rows identical)

    stage(0, 0);
    stage(1, 1);
    int cur = 0;
    for (int t = 0; t <= tB; ++t) {
        int kt = t * 64;
        if (t < tB) asm volatile("s_waitcnt vmcnt(2)" ::: "memory");
        else        asm volatile("s_waitcnt vmcnt(0)" ::: "memory");
        asm volatile("s_barrier" ::: "memory");
        if (t + 2 <= tB) {
            int nxt = cur + 2; if (nxt >= 3) nxt -= 3;
            stage(t + 2, nxt);
        }

        if (t <= myT) {                   // wave-uniform: body only while tile active
            const _Float16* kb = &KV[cur * 8192];
            const _Float16* vb = &KV[cur * 8192 + 4096];
            f16x8 bk[4][2];
#pragma unroll
            for (int s = 0; s < 4; ++s) {
                const _Float16* kr = kb + (s * 16 + m16) * 64;
                bk[s][0] = *(const f16x8*)(kr + cka);
                bk[s][1] = *(const f16x8*)(kr + ckb);
            }
            f16x4 av[4][4];              // [c d-block][s key-chunk]
#pragma unroll
            for (int c = 0; c < 4; ++c) {
                const _Float16* vr = vb + (c * 16 + m16) * 64;
#pragma unroll
                for (int s = 0; s < 4; ++s)
                    av[c][s] = *(const f16x4*)(vr + vco[s]);
            }

            f32x4 st[4];
#pragma unroll
            for (int s = 0; s < 4; ++s) {
                st[s] = MFMA16(bk[s][0], aq0, zero4);
                st[s] = MFMA16(bk[s][1], aq1, st[s]);
            }
            f16x4 pt[4];
            if (t == myT) {              // masked (diagonal) tile
#pragma unroll
                for (int s = 0; s < 4; ++s)
#pragma unroll
                    for (int r = 0; r < 4; ++r) {
                        float p = fexp2(st[s][r]);
                        int key = kt + s * 16 + quad * 4 + r;
                        if (key > q) p = 0.f;
                        pt[s][r] = (_Float16)p;
                    }
            } else {
#pragma unroll
                for (int s = 0; s < 4; ++s)
#pragma unroll
                    for (int r = 0; r < 4; ++r)
                        pt[s][r] = (_Float16)fexp2(st[s][r]);
            }
#pragma unroll
            for (int s = 0; s < 4; ++s)
                lacc = MFMA16K16(ones4, pt[s], lacc);
#pragma unroll
            for (int c = 0; c < 4; ++c)
#pragma unroll
                for (int s = 0; s < 4; ++s)
                    o[c] = MFMA16K16(av[c][s], pt[s], o[c]);
        }

        cur = (cur == 2) ? 0 : cur + 1;
    }

    // epilogue: normalize (denominator identical across rows/quads for a given q), store O^T
    float inv = 1.0f / lacc[0];
    size_t rowoff = ((size_t)(b * SS) + q) * HH + h * HDD;
#pragma unroll
    for (int c = 0; c < 4; ++c) {
        f16x4 ov;
#pragma unroll
        for (int r = 0; r < 4; ++r) ov[r] = (_Float16)(o[c][r] * inv);
        *(f16x4*)&Ctx[rowoff + c * 16 + quad * 4] = ov;
    }
}

extern "C" void kernel_launch(void* const* d_in, const int* in_sizes, int n_in,
                              void* d_out, int out_size, void* d_ws, size_t ws_size,
                              hipStream_t stream) {
    const float* hs = (const float*)d_in[0];
    const float* Wq = (const float*)d_in[1];
    const float* bq = (const float*)d_in[2];
    const float* Wk = (const float*)d_in[3];
    const float* bk = (const float*)d_in[4];
    const float* Wv = (const float*)d_in[5];
    const float* bv = (const float*)d_in[6];
    const float* Wo = (const float*)d_in[7];
    const float* bo = (const float*)d_in[8];
    float* out = (float*)d_out;

    size_t off = 0;
    auto alloc = [&](size_t bytes) {
        void* p = (char*)d_ws + off;
        off += (bytes + 255) & ~(size_t)255;
        return p;
    };
    _Float16* Xh    = (_Float16*)alloc((size_t)MM * HH * 2);
    _Float16* WqkvT = (_Float16*)alloc((size_t)3 * HH * HH * 2);
    _Float16* WoT   = (_Float16*)alloc((size_t)HH * HH * 2);
    _Float16* Qh    = (_Float16*)alloc((size_t)BB * NHH * SS * HDD * 2);
    _Float16* Kh    = (_Float16*)alloc((size_t)BB * NHH * SS * HDD * 2);
    _Float16* Vt    = (_Float16*)alloc((size_t)BB * NHH * SS * HDD * 2);
    _Float16* Ctx   = (_Float16*)alloc((size_t)MM * HH * 2);

    prep_kernel<<<dim3(16, 16, 5), 256, 0, stream>>>(
        hs, Wq, Wk, Wv, Wo, Xh, WqkvT, WoT);
    gemm_qkv_kernel<<<dim3(QKV_N / 128, MM / 128), 256, 0, stream>>>(
        Xh, WqkvT, bq, bk, bv, Qh, Kh, Vt);
    attn_kernel<<<dim3(16, NHH, BB), 512, 0, stream>>>(Qh, Kh, Vt, Ctx);
    gemm_out_kernel<<<dim3(HH / 128, MM / 128), 512, 0, stream>>>(
        Ctx, WoT, bo, out);
}